// Round 8
// baseline (152.118 us; speedup 1.0000x reference)
//
#include <hip/hip_runtime.h>

typedef __attribute__((ext_vector_type(8))) short s16x8;
typedef __attribute__((ext_vector_type(4))) float f32x4;
typedef __attribute__((ext_vector_type(4))) unsigned u32x4;

namespace {
constexpr int kCS = 256, kDH = 64, kDS = 128, kBH = 512;
constexpr float kAlpha = 0.5f;

// Y-path LDS (34816 B)
constexpr int OFF_AC   = 0;                  // ac: 256 f32
constexpr int OFF_ENEG = 1024;               // eneg: 256 f32
constexpr int OFF_B    = 2048;               // Bhi [32][128] s16 (8KB); HThi [64][128] (16KB) aliases B+BLO
constexpr int OFF_BLO  = OFF_B + 8192;       // Blo
constexpr int OFF_XT   = OFF_B + 16384;      // XThi [64][32] s16 (4KB); HTlo (16KB) aliases XT..S end
constexpr int OFF_XTLO = OFF_XT + 4096;      // XTlo
constexpr int OFF_S    = OFF_XTLO + 4096;    // S~hi per-wave [16][32] s16, 8 waves (8KB); cumsum partials early
constexpr int LDS_BYTES = OFF_S + 8192;      // 34816

// hend-path aliases
constexpr int HOFF_BT   = 2048;              // BThi [128][32] s16 (8KB)
constexpr int HOFF_BTLO = HOFF_BT + 8192;
constexpr int HOFF_XT   = HOFF_BT + 16384;   // weighted XT [64][32]
constexpr int HOFF_XTLO = HOFF_XT + 4096;
}

union F4 { float4 v; float f[4]; };

// packed f32x2 -> bf16x2 (RNE), 1 VALU inst
__device__ __forceinline__ unsigned cvt_pk_bf16(float a, float b) {
  unsigned r;
  asm("v_cvt_pk_bf16_f32 %0, %1, %2" : "=v"(r) : "v"(a), "v"(b));
  return r;
}

__device__ __forceinline__ unsigned short bf16_1(float x) {
  return (unsigned short)cvt_pk_bf16(x, x);
}

__device__ __forceinline__ void split2(float a, float b, unsigned& h, unsigned& l) {
  h = cvt_pk_bf16(a, b);
  l = cvt_pk_bf16(a - __uint_as_float(h << 16), b - __uint_as_float(h & 0xFFFF0000u));
}

__device__ __forceinline__ void split8v(float4 a, float4 b, s16x8& hi, s16x8& lo) {
  unsigned h0, h1, h2, h3, l0, l1, l2, l3;
  split2(a.x, a.y, h0, l0);
  split2(a.z, a.w, h1, l1);
  split2(b.x, b.y, h2, l2);
  split2(b.z, b.w, h3, l3);
  u32x4 H = {h0, h1, h2, h3}, L = {l0, l1, l2, l3};
  hi = __builtin_bit_cast(s16x8, H);
  lo = __builtin_bit_cast(s16x8, L);
}

__device__ __forceinline__ void split8s(float x0, float x1, float x2, float x3,
                                        float x4, float x5, float x6, float x7,
                                        s16x8& hi, s16x8& lo) {
  unsigned h0, h1, h2, h3, l0, l1, l2, l3;
  split2(x0, x1, h0, l0);
  split2(x2, x3, h1, l1);
  split2(x4, x5, h2, l2);
  split2(x6, x7, h3, l3);
  u32x4 H = {h0, h1, h2, h3}, L = {l0, l1, l2, l3};
  hi = __builtin_bit_cast(s16x8, H);
  lo = __builtin_bit_cast(s16x8, L);
}

// barrier that waits only this wave's LDS ops -> prefetch vmcnt stays in flight
__device__ __forceinline__ void lds_barrier() {
  asm volatile("s_waitcnt lgkmcnt(0)" ::: "memory");
  __builtin_amdgcn_s_barrier();
  __builtin_amdgcn_sched_barrier(0);
}

// Grid 1024 x 512 threads. bidx<512 -> Y block (one per bh, 8 waves, wave rb
// owns i-rows [32rb,32rb+32), active iff rb>=jt). bidx>=512 -> hend MFMA
// block. bh swizzle keeps a bh's Y and hend on the same XCD slot.
__global__ __launch_bounds__(512, 4) void fused_kernel(
    const float* __restrict__ Xg, const float* __restrict__ Ag,
    const float* __restrict__ Bg, const float* __restrict__ Cg,
    const float* __restrict__ Hg, float* __restrict__ Yg,
    float* __restrict__ hend, float* __restrict__ dtot) {
  __shared__ __align__(16) char smem[LDS_BYTES];
  const int bidx = blockIdx.x;
  const int tid = threadIdx.x;
  const int lane = tid & 63;
  const int w = tid >> 6;          // 0..7
  const int fr = lane & 15;
  const int fg = lane >> 4;

  const int p = bidx & 511;
  const int bh = (p & 7) * 64 + (p >> 3);   // XCD-chunk swizzle, bijective

  const float* Xb = Xg + (size_t)bh * kCS * kDH;
  const float* Ab = Ag + (size_t)bh * kCS;
  const float* Bb = Bg + (size_t)bh * kCS * kDS;
  const float* Hb = Hg + (size_t)bh * kDS * kDH;

  if (bidx >= 512) {
    // ======================= h_end path (8-wave MFMA GEMM) =======================
    float* ac   = (float*)(smem + OFF_AC);
    short* BThi = (short*)(smem + HOFF_BT);
    short* BTlo = (short*)(smem + HOFF_BTLO);
    short* XThi = (short*)(smem + HOFF_XT);
    short* XTlo = (short*)(smem + HOFF_XTLO);
    float* Ob = hend + (size_t)bh * kDS * kDH;

    float v = 0.f;
    if (tid < 256) {
      v = Ab[tid];
#pragma unroll
      for (int off = 1; off < 64; off <<= 1) {
        float t = __shfl_up(v, off);
        if (lane >= off) v += t;
      }
      float* wsum = (float*)(smem + HOFF_BT);
      if (lane == 63) wsum[w] = v;
    }
    __syncthreads();
    if (tid < 256) {
      const float* wsum = (const float*)(smem + HOFF_BT);
      float base = 0.f;
#pragma unroll
      for (int k = 0; k < 4; ++k)
        if (k < w) base += wsum[k];
      ac[tid] = v + base;
    }
    __syncthreads();
    const float alast = ac[kCS - 1];
    if (tid == 0) dtot[bh] = __expf(alast);

    f32x4 acc[4];
#pragma unroll
    for (int dg = 0; dg < 4; ++dg)
#pragma unroll
      for (int r = 0; r < 4; ++r) acc[dg][r] = 0.f;

    const int sblk = tid & 31;
    const int tq = (tid >> 5) & 7;
    const int st = w * 16 + fr;

    for (int t0 = 0; t0 < kCS; t0 += 32) {
      if (tid < 256) {
        // stage B^T [128s][32t] hi/lo via 4x4 micro-transpose
        F4 hr[4];
#pragma unroll
        for (int r = 0; r < 4; ++r)
          hr[r].v = *(const float4*)&Bb[(size_t)(t0 + tq * 4 + r) * kDS + sblk * 4];
#pragma unroll
        for (int c = 0; c < 4; ++c) {
          const int s2 = sblk * 4 + c;
          unsigned h0, h1, l0, l1;
          split2(hr[0].f[c], hr[1].f[c], h0, l0);
          split2(hr[2].f[c], hr[3].f[c], h1, l1);
          const int off = s2 * 32 + (((tq >> 1) ^ ((s2 >> 2) & 3)) << 3) + ((tq & 1) << 2);
          ((unsigned*)&BThi[off])[0] = h0;
          ((unsigned*)&BThi[off])[1] = h1;
          ((unsigned*)&BTlo[off])[0] = l0;
          ((unsigned*)&BTlo[off])[1] = l1;
        }
      } else {
        // stage weighted X^T [64d][32t] hi/lo
        const int t2 = tid - 256;
        const int d = t2 & 63;
        const int wx = t2 >> 6;
        const float* xp = &Xb[(size_t)(t0 + wx * 8) * kDH + d];
        const float* ap = &ac[t0 + wx * 8];
        float w0 = __expf(alast - ap[0]), w1 = __expf(alast - ap[1]);
        float w2 = __expf(alast - ap[2]), w3 = __expf(alast - ap[3]);
        float w4 = __expf(alast - ap[4]), w5 = __expf(alast - ap[5]);
        float w6 = __expf(alast - ap[6]), w7 = __expf(alast - ap[7]);
        s16x8 h8, l8;
        split8s(xp[0 * kDH] * w0, xp[1 * kDH] * w1, xp[2 * kDH] * w2, xp[3 * kDH] * w3,
                xp[4 * kDH] * w4, xp[5 * kDH] * w5, xp[6 * kDH] * w6, xp[7 * kDH] * w7,
                h8, l8);
        const int off = d * 32 + ((wx ^ ((d >> 2) & 3)) << 3);
        *(s16x8*)&XThi[off] = h8;
        *(s16x8*)&XTlo[off] = l8;
      }
      __syncthreads();
      const int aoff = st * 32 + ((fg ^ ((st >> 2) & 3)) << 3);
      s16x8 ah = *(const s16x8*)&BThi[aoff];
      s16x8 al = *(const s16x8*)&BTlo[aoff];
#pragma unroll
      for (int dg = 0; dg < 4; ++dg) {
        const int drow = dg * 16 + fr;
        const int xoff = drow * 32 + ((fg ^ ((drow >> 2) & 3)) << 3);
        s16x8 xh = *(const s16x8*)&XThi[xoff];
        s16x8 xl = *(const s16x8*)&XTlo[xoff];
        acc[dg] = __builtin_amdgcn_mfma_f32_16x16x32_bf16(ah, xh, acc[dg], 0, 0, 0);
        acc[dg] = __builtin_amdgcn_mfma_f32_16x16x32_bf16(ah, xl, acc[dg], 0, 0, 0);
        acc[dg] = __builtin_amdgcn_mfma_f32_16x16x32_bf16(al, xh, acc[dg], 0, 0, 0);
      }
      __syncthreads();
    }
    const float dscale = kAlpha * __expf(alast);
    const float sc = 1.f - kAlpha;
#pragma unroll
    for (int dg = 0; dg < 4; ++dg) {
#pragma unroll
      for (int r = 0; r < 4; ++r) {
        const int s = w * 16 + fg * 4 + r;
        const int d = dg * 16 + fr;
        Ob[(size_t)s * kDH + d] = dscale * Hb[(size_t)s * kDH + d] + sc * acc[dg][r];
      }
    }
    return;
  }

  // ======================= Y path (one block per bh) =======================
  // SIMD-balanced wave->rowblock map: pairs (0,7),(1,6),(2,5),(3,4) share SIMD.
  const int rb = (w < 4) ? w : (11 - w);
  const int i0g = rb * 32;

  float* ac   = (float*)(smem + OFF_AC);
  float* eneg = (float*)(smem + OFF_ENEG);
  short* Bhi  = (short*)(smem + OFF_B);
  short* Blo  = (short*)(smem + OFF_BLO);
  short* XThi = (short*)(smem + OFF_XT);
  short* XTlo = (short*)(smem + OFF_XTLO);
  short* Sall = (short*)(smem + OFF_S);
  short* HThi = (short*)(smem + OFF_B);   // [64][128] h_prev^T hi (16KB)
  short* HTlo = (short*)(smem + OFF_XT);  // lo (16KB)

  const float* Cg_b = Cg + (size_t)bh * kCS * kDS;
  float* Yb = Yg + (size_t)bh * kCS * kDH;

  // ---- cumsum via wave shuffle scan (waves 0-3)
  {
    float v = 0.f;
    if (tid < 256) {
      v = Ab[tid];
#pragma unroll
      for (int off = 1; off < 64; off <<= 1) {
        float t = __shfl_up(v, off);
        if (lane >= off) v += t;
      }
      float* wsum = (float*)(smem + OFF_S);
      if (lane == 63) wsum[w] = v;
    }
    __syncthreads();
    if (tid < 256) {
      const float* wsum = (const float*)(smem + OFF_S);
      float base = 0.f;
#pragma unroll
      for (int k = 0; k < 4; ++k)
        if (k < w) base += wsum[k];
      const float a = v + base;
      ac[tid] = a;
      eneg[tid] = __expf(-a);
    }
    __syncthreads();
  }

  float eaci[2][4];
#pragma unroll
  for (int g = 0; g < 2; ++g)
#pragma unroll
    for (int r = 0; r < 4; ++r)
      eaci[g][r] = __expf(ac[i0g + g * 16 + fg * 4 + r]);

  // ---- C fragments direct from global (read-once; 64B-granular per row)
  s16x8 chi[2][4], clo[2][4];
#pragma unroll
  for (int g = 0; g < 2; ++g) {
    const float* crow = &Cg_b[(size_t)(i0g + g * 16 + fr) * kDS];
#pragma unroll
    for (int kc = 0; kc < 4; ++kc) {
      F4 u0, u1;
      u0.v = *(const float4*)&crow[kc * 32 + fg * 8];
      u1.v = *(const float4*)&crow[kc * 32 + fg * 8 + 4];
      split8v(u0.v, u1.v, chi[g][kc], clo[g][kc]);
    }
  }

  // ---- jt=0 prefetch: every thread loads 8 B-floats + 4 X-floats
  const int brow = tid >> 4;       // 0..31
  const int bg = tid & 15;
  const int xd = lane;             // d index
  const int xq = w;                // t-quad 0..7
  float4 pb0, pb1;
  float px0, px1, px2, px3;
  {
    pb0 = *(const float4*)&Bb[(size_t)brow * kDS + bg * 8];
    pb1 = *(const float4*)&Bb[(size_t)brow * kDS + bg * 8 + 4];
    const float* xp = &Xb[(size_t)(xq * 4) * kDH + xd];
    px0 = xp[0 * kDH]; px1 = xp[1 * kDH]; px2 = xp[2 * kDH]; px3 = xp[3 * kDH];
  }

  f32x4 yacc[2][4];
#pragma unroll
  for (int g = 0; g < 2; ++g)
#pragma unroll
    for (int n = 0; n < 4; ++n)
#pragma unroll
      for (int r = 0; r < 4; ++r) yacc[g][n][r] = 0.f;

  short* Sp = Sall + w * 512;  // per-wave S~ plane [16][32], reused per g

  for (int jt = 0; jt < 8; ++jt) {
    // ---- split+write current tile from named prefetch regs
    {
      s16x8 h8, l8;
      split8v(pb0, pb1, h8, l8);
      const int col = (bg ^ (brow & 7)) * 8;
      *(s16x8*)&Bhi[brow * 128 + col] = h8;
      *(s16x8*)&Blo[brow * 128 + col] = l8;
    }
    {
      unsigned h0, h1, l0, l1;
      split2(px0, px1, h0, l0);
      split2(px2, px3, h1, l1);
      const int off = xd * 32 + (((xq >> 1) ^ ((xd >> 2) & 3)) << 3) + ((xq & 1) << 2);
      ((unsigned*)&XThi[off])[0] = h0;
      ((unsigned*)&XThi[off])[1] = h1;
      ((unsigned*)&XTlo[off])[0] = l0;
      ((unsigned*)&XTlo[off])[1] = l1;
    }
    // ---- issue next tile's loads; stay in flight across both lds_barriers
    if (jt + 1 < 8) {
      const int j0n = (jt + 1) * 32;
      pb0 = *(const float4*)&Bb[(size_t)(j0n + brow) * kDS + bg * 8];
      pb1 = *(const float4*)&Bb[(size_t)(j0n + brow) * kDS + bg * 8 + 4];
      const float* xp = &Xb[(size_t)(j0n + xq * 4) * kDH + xd];
      px0 = xp[0 * kDH]; px1 = xp[1 * kDH]; px2 = xp[2 * kDH]; px3 = xp[3 * kDH];
    }
    lds_barrier();

    if (rb >= jt) {
      const int j0 = jt * 32;
#pragma unroll
      for (int g = 0; g < 2; ++g) {
        // ---- S = C·B^T, split hi/lo products, split accumulator chains
        f32x4 sA[2], sB[2];
#pragma unroll
        for (int n = 0; n < 2; ++n) {
#pragma unroll
          for (int r = 0; r < 4; ++r) { sA[n][r] = 0.f; sB[n][r] = 0.f; }
          const int jrow = n * 16 + fr;
          const short* bph = &Bhi[jrow * 128];
          const short* bpl = &Blo[jrow * 128];
#pragma unroll
          for (int kc = 0; kc < 2; ++kc) {
            const int phys = ((4 * kc + fg) ^ (jrow & 7)) * 8;
            s16x8 b8 = *(const s16x8*)&bph[phys];
            s16x8 l8 = *(const s16x8*)&bpl[phys];
            sA[n] = __builtin_amdgcn_mfma_f32_16x16x32_bf16(chi[g][kc], b8, sA[n], 0, 0, 0);
            sA[n] = __builtin_amdgcn_mfma_f32_16x16x32_bf16(chi[g][kc], l8, sA[n], 0, 0, 0);
            sA[n] = __builtin_amdgcn_mfma_f32_16x16x32_bf16(clo[g][kc], b8, sA[n], 0, 0, 0);
          }
#pragma unroll
          for (int kc = 2; kc < 4; ++kc) {
            const int phys = ((4 * kc + fg) ^ (jrow & 7)) * 8;
            s16x8 b8 = *(const s16x8*)&bph[phys];
            s16x8 l8 = *(const s16x8*)&bpl[phys];
            sB[n] = __builtin_amdgcn_mfma_f32_16x16x32_bf16(chi[g][kc], b8, sB[n], 0, 0, 0);
            sB[n] = __builtin_amdgcn_mfma_f32_16x16x32_bf16(chi[g][kc], l8, sB[n], 0, 0, 0);
            sB[n] = __builtin_amdgcn_mfma_f32_16x16x32_bf16(clo[g][kc], b8, sB[n], 0, 0, 0);
          }
        }
        // ---- mask + decay, write S~ to per-wave plane
#pragma unroll
        for (int n = 0; n < 2; ++n) {
          const int jg = j0 + n * 16 + fr;
          const float enj = eneg[jg];
#pragma unroll
          for (int r = 0; r < 4; ++r) {
            const int iwl = fg * 4 + r;
            const int ig = i0g + g * 16 + iwl;
            float sv = (sA[n][r] + sB[n][r]) * eaci[g][r] * enj;
            sv = (jg <= ig) ? sv : 0.f;
            Sp[iwl * 32 + (((n * 2 + (fr >> 3)) ^ fg) << 3) + (fr & 7)] = (short)bf16_1(sv);
          }
        }
        // ---- PV: Y += S~ · X
        {
          s16x8 sa = *(const s16x8*)&Sp[fr * 32 + ((fg ^ (fr >> 2)) << 3)];
#pragma unroll
          for (int n = 0; n < 4; ++n) {
            const int drow = n * 16 + fr;
            const int pxo = (fg ^ ((drow >> 2) & 3)) << 3;
            s16x8 xh = *(const s16x8*)&XThi[drow * 32 + pxo];
            s16x8 xl = *(const s16x8*)&XTlo[drow * 32 + pxo];
            yacc[g][n] = __builtin_amdgcn_mfma_f32_16x16x32_bf16(sa, xh, yacc[g][n], 0, 0, 0);
            yacc[g][n] = __builtin_amdgcn_mfma_f32_16x16x32_bf16(sa, xl, yacc[g][n], 0, 0, 0);
          }
        }
      }
    }
    lds_barrier();
  }

  // ---- Yh = C · h_prev: full h_prev^T staged once, all waves MFMA
  __syncthreads();
  {
    const int dd = tid & 15, tt = tid >> 4;  // tt 0..31 -> full 128 s
    F4 hr[4];
#pragma unroll
    for (int r = 0; r < 4; ++r)
      hr[r].v = *(const float4*)&Hb[(size_t)(tt * 4 + r) * kDH + dd * 4];
#pragma unroll
    for (int c = 0; c < 4; ++c) {
      const int d = dd * 4 + c;
      unsigned h0, h1, l0, l1;
      split2(hr[0].f[c], hr[1].f[c], h0, l0);
      split2(hr[2].f[c], hr[3].f[c], h1, l1);
      const int off = d * 128 + (((tt >> 1) ^ (d & 7)) << 3) + ((tt & 1) << 2);
      ((unsigned*)&HThi[off])[0] = h0;
      ((unsigned*)&HThi[off])[1] = h1;
      ((unsigned*)&HTlo[off])[0] = l0;
      ((unsigned*)&HTlo[off])[1] = l1;
    }
  }
  __syncthreads();

#pragma unroll
  for (int g = 0; g < 2; ++g) {
    f32x4 yh[4];
#pragma unroll
    for (int n = 0; n < 4; ++n)
#pragma unroll
      for (int r = 0; r < 4; ++r) yh[n][r] = 0.f;
#pragma unroll
    for (int kc = 0; kc < 4; ++kc) {
#pragma unroll
      for (int n = 0; n < 4; ++n) {
        const int drow = n * 16 + fr;
        const int phys = ((4 * kc + fg) ^ (drow & 7)) * 8;
        s16x8 hh = *(const s16x8*)&HThi[drow * 128 + phys];
        s16x8 hl = *(const s16x8*)&HTlo[drow * 128 + phys];
        yh[n] = __builtin_amdgcn_mfma_f32_16x16x32_bf16(chi[g][kc], hh, yh[n], 0, 0, 0);
        yh[n] = __builtin_amdgcn_mfma_f32_16x16x32_bf16(chi[g][kc], hl, yh[n], 0, 0, 0);
        yh[n] = __builtin_amdgcn_mfma_f32_16x16x32_bf16(clo[g][kc], hh, yh[n], 0, 0, 0);
      }
    }
    // ---- epilogue for this g: Y = (1-a)*Y_intra + a*exp(ac_i)*Yh
#pragma unroll
    for (int n = 0; n < 4; ++n) {
#pragma unroll
      for (int r = 0; r < 4; ++r) {
        const int ig = i0g + g * 16 + fg * 4 + r;
        const int d = n * 16 + fr;
        Yb[(size_t)ig * kDH + d] = (1.f - kAlpha) * yacc[g][n][r] + (kAlpha * eaci[g][r]) * yh[n][r];
      }
    }
  }
}

extern "C" void kernel_launch(void* const* d_in, const int* in_sizes, int n_in,
                              void* d_out, int out_size, void* d_ws, size_t ws_size,
                              hipStream_t stream) {
  const float* X = (const float*)d_in[0];
  const float* A = (const float*)d_in[1];
  const float* B = (const float*)d_in[2];
  const float* C = (const float*)d_in[3];
  const float* H = (const float*)d_in[4];
  float* out = (float*)d_out;
  float* Y = out;
  float* hend = Y + (size_t)kBH * kCS * kDH;
  float* dt = hend + (size_t)kBH * kDS * kDH;

  fused_kernel<<<1024, 512, 0, stream>>>(X, A, B, C, H, Y, hend, dt);
}

// Round 9
// 85.135 us; speedup vs baseline: 1.7868x; 1.7868x over previous
//
#include <hip/hip_runtime.h>

typedef __attribute__((ext_vector_type(8))) short s16x8;
typedef __attribute__((ext_vector_type(4))) float f32x4;
typedef __attribute__((ext_vector_type(4))) unsigned u32x4;

namespace {
constexpr int kCS = 256, kDH = 64, kDS = 128, kBH = 512;
constexpr float kAlpha = 0.5f;

// Y-path LDS (34816 B)
constexpr int OFF_AC   = 0;                  // ac: 256 f32
constexpr int OFF_ENEG = 1024;               // eneg: 256 f32
constexpr int OFF_B    = 2048;               // Bhi [32][128] s16 (8KB); HThi [64][128] (16KB) aliases B+BLO
constexpr int OFF_BLO  = OFF_B + 8192;       // Blo
constexpr int OFF_XT   = OFF_B + 16384;      // XThi [64][32] s16 (4KB); HTlo (16KB) aliases XT..S end
constexpr int OFF_XTLO = OFF_XT + 4096;      // XTlo
constexpr int OFF_S    = OFF_XTLO + 4096;    // S~hi per-wave [16][32] s16, 8 waves (8KB); cumsum partials early
constexpr int LDS_BYTES = OFF_S + 8192;      // 34816

// hend-path aliases
constexpr int HOFF_BT   = 2048;              // BThi [128][32] s16 (8KB)
constexpr int HOFF_BTLO = HOFF_BT + 8192;
constexpr int HOFF_XT   = HOFF_BT + 16384;   // weighted XT [64][32]
constexpr int HOFF_XTLO = HOFF_XT + 4096;
}

union F4 { float4 v; float f[4]; };

// packed f32x2 -> bf16x2 (RNE), 1 VALU inst
__device__ __forceinline__ unsigned cvt_pk_bf16(float a, float b) {
  unsigned r;
  asm("v_cvt_pk_bf16_f32 %0, %1, %2" : "=v"(r) : "v"(a), "v"(b));
  return r;
}

__device__ __forceinline__ unsigned short bf16_1(float x) {
  return (unsigned short)cvt_pk_bf16(x, x);
}

__device__ __forceinline__ void split2(float a, float b, unsigned& h, unsigned& l) {
  h = cvt_pk_bf16(a, b);
  l = cvt_pk_bf16(a - __uint_as_float(h << 16), b - __uint_as_float(h & 0xFFFF0000u));
}

__device__ __forceinline__ void split8v(float4 a, float4 b, s16x8& hi, s16x8& lo) {
  unsigned h0, h1, h2, h3, l0, l1, l2, l3;
  split2(a.x, a.y, h0, l0);
  split2(a.z, a.w, h1, l1);
  split2(b.x, b.y, h2, l2);
  split2(b.z, b.w, h3, l3);
  u32x4 H = {h0, h1, h2, h3}, L = {l0, l1, l2, l3};
  hi = __builtin_bit_cast(s16x8, H);
  lo = __builtin_bit_cast(s16x8, L);
}

__device__ __forceinline__ void split8s(float x0, float x1, float x2, float x3,
                                        float x4, float x5, float x6, float x7,
                                        s16x8& hi, s16x8& lo) {
  unsigned h0, h1, h2, h3, l0, l1, l2, l3;
  split2(x0, x1, h0, l0);
  split2(x2, x3, h1, l1);
  split2(x4, x5, h2, l2);
  split2(x6, x7, h3, l3);
  u32x4 H = {h0, h1, h2, h3}, L = {l0, l1, l2, l3};
  hi = __builtin_bit_cast(s16x8, H);
  lo = __builtin_bit_cast(s16x8, L);
}

// barrier that waits only this wave's LDS ops -> prefetch vmcnt stays in flight
__device__ __forceinline__ void lds_barrier() {
  asm volatile("s_waitcnt lgkmcnt(0)" ::: "memory");
  __builtin_amdgcn_s_barrier();
  __builtin_amdgcn_sched_barrier(0);
}

// Grid 1024 x 512 threads. bidx<512 -> Y block (one per bh, 8 waves, wave rb
// owns i-rows [32rb,32rb+32), active iff rb>=jt). bidx>=512 -> hend MFMA block.
// launch_bounds(512,2): for 8-wave blocks the 2nd arg acts as blocks/CU
// (R8 evidence: arg=4 capped VGPR at 64 -> 170MB scratch spill). 2 -> 128 cap.
__global__ __launch_bounds__(512, 2) void fused_kernel(
    const float* __restrict__ Xg, const float* __restrict__ Ag,
    const float* __restrict__ Bg, const float* __restrict__ Cg,
    const float* __restrict__ Hg, float* __restrict__ Yg,
    float* __restrict__ hend, float* __restrict__ dtot) {
  __shared__ __align__(16) char smem[LDS_BYTES];
  const int bidx = blockIdx.x;
  const int tid = threadIdx.x;
  const int lane = tid & 63;
  const int w = tid >> 6;          // 0..7
  const int fr = lane & 15;
  const int fg = lane >> 4;

  const int p = bidx & 511;
  const int bh = (p & 7) * 64 + (p >> 3);   // XCD-chunk swizzle, bijective

  const float* Xb = Xg + (size_t)bh * kCS * kDH;
  const float* Ab = Ag + (size_t)bh * kCS;
  const float* Bb = Bg + (size_t)bh * kCS * kDS;
  const float* Hb = Hg + (size_t)bh * kDS * kDH;

  if (bidx >= 512) {
    // ======================= h_end path (8-wave MFMA GEMM) =======================
    float* ac   = (float*)(smem + OFF_AC);
    short* BThi = (short*)(smem + HOFF_BT);
    short* BTlo = (short*)(smem + HOFF_BTLO);
    short* XThi = (short*)(smem + HOFF_XT);
    short* XTlo = (short*)(smem + HOFF_XTLO);
    float* Ob = hend + (size_t)bh * kDS * kDH;

    float v = 0.f;
    if (tid < 256) {
      v = Ab[tid];
#pragma unroll
      for (int off = 1; off < 64; off <<= 1) {
        float t = __shfl_up(v, off);
        if (lane >= off) v += t;
      }
      float* wsum = (float*)(smem + HOFF_BT);
      if (lane == 63) wsum[w] = v;
    }
    __syncthreads();
    if (tid < 256) {
      const float* wsum = (const float*)(smem + HOFF_BT);
      float base = 0.f;
#pragma unroll
      for (int k = 0; k < 4; ++k)
        if (k < w) base += wsum[k];
      ac[tid] = v + base;
    }
    __syncthreads();
    const float alast = ac[kCS - 1];
    if (tid == 0) dtot[bh] = __expf(alast);

    f32x4 acc[4];
#pragma unroll
    for (int dg = 0; dg < 4; ++dg)
#pragma unroll
      for (int r = 0; r < 4; ++r) acc[dg][r] = 0.f;

    const int sblk = tid & 31;
    const int tq = (tid >> 5) & 7;
    const int st = w * 16 + fr;

    for (int t0 = 0; t0 < kCS; t0 += 32) {
      if (tid < 256) {
        // stage B^T [128s][32t] hi/lo via 4x4 micro-transpose
        F4 hr[4];
#pragma unroll
        for (int r = 0; r < 4; ++r)
          hr[r].v = *(const float4*)&Bb[(size_t)(t0 + tq * 4 + r) * kDS + sblk * 4];
#pragma unroll
        for (int c = 0; c < 4; ++c) {
          const int s2 = sblk * 4 + c;
          unsigned h0, h1, l0, l1;
          split2(hr[0].f[c], hr[1].f[c], h0, l0);
          split2(hr[2].f[c], hr[3].f[c], h1, l1);
          const int off = s2 * 32 + (((tq >> 1) ^ ((s2 >> 2) & 3)) << 3) + ((tq & 1) << 2);
          ((unsigned*)&BThi[off])[0] = h0;
          ((unsigned*)&BThi[off])[1] = h1;
          ((unsigned*)&BTlo[off])[0] = l0;
          ((unsigned*)&BTlo[off])[1] = l1;
        }
      } else {
        // stage weighted X^T [64d][32t] hi/lo
        const int t2 = tid - 256;
        const int d = t2 & 63;
        const int wx = t2 >> 6;
        const float* xp = &Xb[(size_t)(t0 + wx * 8) * kDH + d];
        const float* ap = &ac[t0 + wx * 8];
        float w0 = __expf(alast - ap[0]), w1 = __expf(alast - ap[1]);
        float w2 = __expf(alast - ap[2]), w3 = __expf(alast - ap[3]);
        float w4 = __expf(alast - ap[4]), w5 = __expf(alast - ap[5]);
        float w6 = __expf(alast - ap[6]), w7 = __expf(alast - ap[7]);
        s16x8 h8, l8;
        split8s(xp[0 * kDH] * w0, xp[1 * kDH] * w1, xp[2 * kDH] * w2, xp[3 * kDH] * w3,
                xp[4 * kDH] * w4, xp[5 * kDH] * w5, xp[6 * kDH] * w6, xp[7 * kDH] * w7,
                h8, l8);
        const int off = d * 32 + ((wx ^ ((d >> 2) & 3)) << 3);
        *(s16x8*)&XThi[off] = h8;
        *(s16x8*)&XTlo[off] = l8;
      }
      __syncthreads();
      const int aoff = st * 32 + ((fg ^ ((st >> 2) & 3)) << 3);
      s16x8 ah = *(const s16x8*)&BThi[aoff];
      s16x8 al = *(const s16x8*)&BTlo[aoff];
#pragma unroll
      for (int dg = 0; dg < 4; ++dg) {
        const int drow = dg * 16 + fr;
        const int xoff = drow * 32 + ((fg ^ ((drow >> 2) & 3)) << 3);
        s16x8 xh = *(const s16x8*)&XThi[xoff];
        s16x8 xl = *(const s16x8*)&XTlo[xoff];
        acc[dg] = __builtin_amdgcn_mfma_f32_16x16x32_bf16(ah, xh, acc[dg], 0, 0, 0);
        acc[dg] = __builtin_amdgcn_mfma_f32_16x16x32_bf16(ah, xl, acc[dg], 0, 0, 0);
        acc[dg] = __builtin_amdgcn_mfma_f32_16x16x32_bf16(al, xh, acc[dg], 0, 0, 0);
      }
      __syncthreads();
    }
    const float dscale = kAlpha * __expf(alast);
    const float sc = 1.f - kAlpha;
#pragma unroll
    for (int dg = 0; dg < 4; ++dg) {
#pragma unroll
      for (int r = 0; r < 4; ++r) {
        const int s = w * 16 + fg * 4 + r;
        const int d = dg * 16 + fr;
        Ob[(size_t)s * kDH + d] = dscale * Hb[(size_t)s * kDH + d] + sc * acc[dg][r];
      }
    }
    return;
  }

  // ======================= Y path (one block per bh) =======================
  // SIMD-balanced wave->rowblock map: pairs (0,7),(1,6),(2,5),(3,4) share SIMD.
  const int rb = (w < 4) ? w : (11 - w);
  const int i0g = rb * 32;

  float* ac   = (float*)(smem + OFF_AC);
  float* eneg = (float*)(smem + OFF_ENEG);
  short* Bhi  = (short*)(smem + OFF_B);
  short* Blo  = (short*)(smem + OFF_BLO);
  short* XThi = (short*)(smem + OFF_XT);
  short* XTlo = (short*)(smem + OFF_XTLO);
  short* Sall = (short*)(smem + OFF_S);
  short* HThi = (short*)(smem + OFF_B);   // [64][128] h_prev^T hi (16KB)
  short* HTlo = (short*)(smem + OFF_XT);  // lo (16KB)

  const float* Cg_b = Cg + (size_t)bh * kCS * kDS;
  float* Yb = Yg + (size_t)bh * kCS * kDH;

  // ---- cumsum via wave shuffle scan (waves 0-3)
  {
    float v = 0.f;
    if (tid < 256) {
      v = Ab[tid];
#pragma unroll
      for (int off = 1; off < 64; off <<= 1) {
        float t = __shfl_up(v, off);
        if (lane >= off) v += t;
      }
      float* wsum = (float*)(smem + OFF_S);
      if (lane == 63) wsum[w] = v;
    }
    __syncthreads();
    if (tid < 256) {
      const float* wsum = (const float*)(smem + OFF_S);
      float base = 0.f;
#pragma unroll
      for (int k = 0; k < 4; ++k)
        if (k < w) base += wsum[k];
      const float a = v + base;
      ac[tid] = a;
      eneg[tid] = __expf(-a);
    }
    __syncthreads();
  }

  float eaci[2][4];
#pragma unroll
  for (int g = 0; g < 2; ++g)
#pragma unroll
    for (int r = 0; r < 4; ++r)
      eaci[g][r] = __expf(ac[i0g + g * 16 + fg * 4 + r]);

  // ---- C fragments direct from global (read-once; 128B-contiguous per row)
  s16x8 chi[2][4], clo[2][4];
#pragma unroll
  for (int g = 0; g < 2; ++g) {
    const float* crow = &Cg_b[(size_t)(i0g + g * 16 + fr) * kDS];
#pragma unroll
    for (int kc = 0; kc < 4; ++kc) {
      F4 u0, u1;
      u0.v = *(const float4*)&crow[kc * 32 + fg * 8];
      u1.v = *(const float4*)&crow[kc * 32 + fg * 8 + 4];
      split8v(u0.v, u1.v, chi[g][kc], clo[g][kc]);
    }
  }

  // ---- jt=0 prefetch: every thread loads 8 B-floats + 4 X-floats
  const int brow = tid >> 4;       // 0..31
  const int bg = tid & 15;
  const int xd = lane;             // d index
  const int xq = w;                // t-quad 0..7
  float4 pb0, pb1;
  float px0, px1, px2, px3;
  {
    pb0 = *(const float4*)&Bb[(size_t)brow * kDS + bg * 8];
    pb1 = *(const float4*)&Bb[(size_t)brow * kDS + bg * 8 + 4];
    const float* xp = &Xb[(size_t)(xq * 4) * kDH + xd];
    px0 = xp[0 * kDH]; px1 = xp[1 * kDH]; px2 = xp[2 * kDH]; px3 = xp[3 * kDH];
  }

  f32x4 yacc[2][4];
#pragma unroll
  for (int g = 0; g < 2; ++g)
#pragma unroll
    for (int n = 0; n < 4; ++n)
#pragma unroll
      for (int r = 0; r < 4; ++r) yacc[g][n][r] = 0.f;

  short* Sp = Sall + w * 512;  // per-wave S~ plane [16][32], reused per g

  for (int jt = 0; jt < 8; ++jt) {
    // ---- split+write current tile from named prefetch regs
    {
      s16x8 h8, l8;
      split8v(pb0, pb1, h8, l8);
      const int col = (bg ^ (brow & 7)) * 8;
      *(s16x8*)&Bhi[brow * 128 + col] = h8;
      *(s16x8*)&Blo[brow * 128 + col] = l8;
    }
    {
      unsigned h0, h1, l0, l1;
      split2(px0, px1, h0, l0);
      split2(px2, px3, h1, l1);
      const int off = xd * 32 + (((xq >> 1) ^ ((xd >> 2) & 3)) << 3) + ((xq & 1) << 2);
      ((unsigned*)&XThi[off])[0] = h0;
      ((unsigned*)&XThi[off])[1] = h1;
      ((unsigned*)&XTlo[off])[0] = l0;
      ((unsigned*)&XTlo[off])[1] = l1;
    }
    // ---- issue next tile's loads; stay in flight across both lds_barriers
    if (jt + 1 < 8) {
      const int j0n = (jt + 1) * 32;
      pb0 = *(const float4*)&Bb[(size_t)(j0n + brow) * kDS + bg * 8];
      pb1 = *(const float4*)&Bb[(size_t)(j0n + brow) * kDS + bg * 8 + 4];
      const float* xp = &Xb[(size_t)(j0n + xq * 4) * kDH + xd];
      px0 = xp[0 * kDH]; px1 = xp[1 * kDH]; px2 = xp[2 * kDH]; px3 = xp[3 * kDH];
    }
    lds_barrier();

    if (rb >= jt) {
      const int j0 = jt * 32;
#pragma unroll
      for (int g = 0; g < 2; ++g) {
        // ---- S = C·B^T (split hi/lo products, single accumulator chain)
        f32x4 s[2];
#pragma unroll
        for (int n = 0; n < 2; ++n) {
#pragma unroll
          for (int r = 0; r < 4; ++r) s[n][r] = 0.f;
          const int jrow = n * 16 + fr;
          const short* bph = &Bhi[jrow * 128];
          const short* bpl = &Blo[jrow * 128];
#pragma unroll
          for (int kc = 0; kc < 4; ++kc) {
            const int phys = ((4 * kc + fg) ^ (jrow & 7)) * 8;
            s16x8 b8 = *(const s16x8*)&bph[phys];
            s16x8 l8 = *(const s16x8*)&bpl[phys];
            s[n] = __builtin_amdgcn_mfma_f32_16x16x32_bf16(chi[g][kc], b8, s[n], 0, 0, 0);
            s[n] = __builtin_amdgcn_mfma_f32_16x16x32_bf16(chi[g][kc], l8, s[n], 0, 0, 0);
            s[n] = __builtin_amdgcn_mfma_f32_16x16x32_bf16(clo[g][kc], b8, s[n], 0, 0, 0);
          }
        }
        // ---- mask + decay, write S~ to per-wave plane
#pragma unroll
        for (int n = 0; n < 2; ++n) {
          const int jg = j0 + n * 16 + fr;
          const float enj = eneg[jg];
#pragma unroll
          for (int r = 0; r < 4; ++r) {
            const int iwl = fg * 4 + r;
            const int ig = i0g + g * 16 + iwl;
            float sv = s[n][r] * eaci[g][r] * enj;
            sv = (jg <= ig) ? sv : 0.f;
            Sp[iwl * 32 + (((n * 2 + (fr >> 3)) ^ fg) << 3) + (fr & 7)] = (short)bf16_1(sv);
          }
        }
        // ---- PV: Y += S~ · X
        {
          s16x8 sa = *(const s16x8*)&Sp[fr * 32 + ((fg ^ (fr >> 2)) << 3)];
#pragma unroll
          for (int n = 0; n < 4; ++n) {
            const int drow = n * 16 + fr;
            const int pxo = (fg ^ ((drow >> 2) & 3)) << 3;
            s16x8 xh = *(const s16x8*)&XThi[drow * 32 + pxo];
            s16x8 xl = *(const s16x8*)&XTlo[drow * 32 + pxo];
            yacc[g][n] = __builtin_amdgcn_mfma_f32_16x16x32_bf16(sa, xh, yacc[g][n], 0, 0, 0);
            yacc[g][n] = __builtin_amdgcn_mfma_f32_16x16x32_bf16(sa, xl, yacc[g][n], 0, 0, 0);
          }
        }
      }
    }
    lds_barrier();
  }

  // ---- Yh = C · h_prev: full h_prev^T staged once, all waves MFMA
  __syncthreads();
  {
    const int dd = tid & 15, tt = tid >> 4;  // tt 0..31 -> full 128 s
    F4 hr[4];
#pragma unroll
    for (int r = 0; r < 4; ++r)
      hr[r].v = *(const float4*)&Hb[(size_t)(tt * 4 + r) * kDH + dd * 4];
#pragma unroll
    for (int c = 0; c < 4; ++c) {
      const int d = dd * 4 + c;
      unsigned h0, h1, l0, l1;
      split2(hr[0].f[c], hr[1].f[c], h0, l0);
      split2(hr[2].f[c], hr[3].f[c], h1, l1);
      const int off = d * 128 + (((tt >> 1) ^ (d & 7)) << 3) + ((tt & 1) << 2);
      ((unsigned*)&HThi[off])[0] = h0;
      ((unsigned*)&HThi[off])[1] = h1;
      ((unsigned*)&HTlo[off])[0] = l0;
      ((unsigned*)&HTlo[off])[1] = l1;
    }
  }
  __syncthreads();

#pragma unroll
  for (int g = 0; g < 2; ++g) {
    f32x4 yh[4];
#pragma unroll
    for (int n = 0; n < 4; ++n)
#pragma unroll
      for (int r = 0; r < 4; ++r) yh[n][r] = 0.f;
#pragma unroll
    for (int kc = 0; kc < 4; ++kc) {
#pragma unroll
      for (int n = 0; n < 4; ++n) {
        const int drow = n * 16 + fr;
        const int phys = ((4 * kc + fg) ^ (drow & 7)) * 8;
        s16x8 hh = *(const s16x8*)&HThi[drow * 128 + phys];
        s16x8 hl = *(const s16x8*)&HTlo[drow * 128 + phys];
        yh[n] = __builtin_amdgcn_mfma_f32_16x16x32_bf16(chi[g][kc], hh, yh[n], 0, 0, 0);
        yh[n] = __builtin_amdgcn_mfma_f32_16x16x32_bf16(chi[g][kc], hl, yh[n], 0, 0, 0);
        yh[n] = __builtin_amdgcn_mfma_f32_16x16x32_bf16(clo[g][kc], hh, yh[n], 0, 0, 0);
      }
    }
    // ---- epilogue for this g: Y = (1-a)*Y_intra + a*exp(ac_i)*Yh
#pragma unroll
    for (int n = 0; n < 4; ++n) {
#pragma unroll
      for (int r = 0; r < 4; ++r) {
        const int ig = i0g + g * 16 + fg * 4 + r;
        const int d = n * 16 + fr;
        Yb[(size_t)ig * kDH + d] = (1.f - kAlpha) * yacc[g][n][r] + (kAlpha * eaci[g][r]) * yh[n][r];
      }
    }
  }
}

extern "C" void kernel_launch(void* const* d_in, const int* in_sizes, int n_in,
                              void* d_out, int out_size, void* d_ws, size_t ws_size,
                              hipStream_t stream) {
  const float* X = (const float*)d_in[0];
  const float* A = (const float*)d_in[1];
  const float* B = (const float*)d_in[2];
  const float* C = (const float*)d_in[3];
  const float* H = (const float*)d_in[4];
  float* out = (float*)d_out;
  float* Y = out;
  float* hend = Y + (size_t)kBH * kCS * kDH;
  float* dt = hend + (size_t)kBH * kDS * kDH;

  fused_kernel<<<1024, 512, 0, stream>>>(X, A, B, C, H, Y, hend, dt);
}

// Round 10
// 67.250 us; speedup vs baseline: 2.2620x; 1.2659x over previous
//
#include <hip/hip_runtime.h>

typedef __attribute__((ext_vector_type(8))) short s16x8;
typedef __attribute__((ext_vector_type(4))) float f32x4;
typedef __attribute__((ext_vector_type(4))) unsigned u32x4;

namespace {
constexpr int kCS = 256, kDH = 64, kDS = 128, kBH = 512;
constexpr float kAlpha = 0.5f;

// Y-path LDS (34816 B)
constexpr int OFF_AC   = 0;                  // ac: 256 f32
constexpr int OFF_ENEG = 1024;               // eneg: 256 f32
constexpr int OFF_B    = 2048;               // Bhi [32][128] s16 (8KB); HThi [64][128] (16KB) aliases B+BLO
constexpr int OFF_BLO  = OFF_B + 8192;       // Blo
constexpr int OFF_XT   = OFF_B + 16384;      // XThi [64][32] s16 (4KB); HTlo (16KB) aliases XT..S end
constexpr int OFF_XTLO = OFF_XT + 4096;      // XTlo
constexpr int OFF_S    = OFF_XTLO + 4096;    // S~hi per-wave [16][32] s16, 8 waves (8KB); cumsum partials early
constexpr int LDS_BYTES = OFF_S + 8192;      // 34816

// hend-path aliases
constexpr int HOFF_BT   = 2048;              // BThi [128][32] s16 (8KB)
constexpr int HOFF_BTLO = HOFF_BT + 8192;
constexpr int HOFF_XT   = HOFF_BT + 16384;   // weighted XT [64][32]
constexpr int HOFF_XTLO = HOFF_XT + 4096;
}

union F4 { float4 v; float f[4]; };

// packed f32x2 -> bf16x2 (RNE), 1 VALU inst
__device__ __forceinline__ unsigned cvt_pk_bf16(float a, float b) {
  unsigned r;
  asm("v_cvt_pk_bf16_f32 %0, %1, %2" : "=v"(r) : "v"(a), "v"(b));
  return r;
}

__device__ __forceinline__ unsigned short bf16_1(float x) {
  return (unsigned short)cvt_pk_bf16(x, x);
}

__device__ __forceinline__ void split2(float a, float b, unsigned& h, unsigned& l) {
  h = cvt_pk_bf16(a, b);
  l = cvt_pk_bf16(a - __uint_as_float(h << 16), b - __uint_as_float(h & 0xFFFF0000u));
}

__device__ __forceinline__ void split8v(float4 a, float4 b, s16x8& hi, s16x8& lo) {
  unsigned h0, h1, h2, h3, l0, l1, l2, l3;
  split2(a.x, a.y, h0, l0);
  split2(a.z, a.w, h1, l1);
  split2(b.x, b.y, h2, l2);
  split2(b.z, b.w, h3, l3);
  u32x4 H = {h0, h1, h2, h3}, L = {l0, l1, l2, l3};
  hi = __builtin_bit_cast(s16x8, H);
  lo = __builtin_bit_cast(s16x8, L);
}

__device__ __forceinline__ void split8s(float x0, float x1, float x2, float x3,
                                        float x4, float x5, float x6, float x7,
                                        s16x8& hi, s16x8& lo) {
  unsigned h0, h1, h2, h3, l0, l1, l2, l3;
  split2(x0, x1, h0, l0);
  split2(x2, x3, h1, l1);
  split2(x4, x5, h2, l2);
  split2(x6, x7, h3, l3);
  u32x4 H = {h0, h1, h2, h3}, L = {l0, l1, l2, l3};
  hi = __builtin_bit_cast(s16x8, H);
  lo = __builtin_bit_cast(s16x8, L);
}

// barrier that waits only this wave's LDS ops -> prefetch vmcnt stays in flight
__device__ __forceinline__ void lds_barrier() {
  asm volatile("s_waitcnt lgkmcnt(0)" ::: "memory");
  __builtin_amdgcn_s_barrier();
  __builtin_amdgcn_sched_barrier(0);
}

// 512-thread blocks, 3 roles per bh: role0 = Y pair (i-tiles 0,3), role1 =
// Y pair (1,2), role2 = hend. (512,4) -> 64-VGPR cap: 4 blocks/CU with mild
// spill, which beat both no-spill/2-block (R9) and heavy-spill (R8).
__global__ __launch_bounds__(512, 4) void fused_kernel(
    const float* __restrict__ Xg, const float* __restrict__ Ag,
    const float* __restrict__ Bg, const float* __restrict__ Cg,
    const float* __restrict__ Hg, float* __restrict__ Yg,
    float* __restrict__ hend, float* __restrict__ dtot) {
  __shared__ __align__(16) char smem[LDS_BYTES];
  const int bidx = blockIdx.x;
  const int tid = threadIdx.x;
  const int lane = tid & 63;
  const int w = tid >> 6;          // 0..7
  const int fr = lane & 15;
  const int fg = lane >> 4;

  // XCD-grouping swizzle: 1536 = 8 XCDs x 192; the 3 blocks of one bh land in
  // the same XCD chunk -> shared L2 for B/C/X/H.
  const int swz = (bidx & 7) * 192 + (bidx >> 3);
  const int role = swz % 3;
  const int bh = swz / 3;

  const float* Xb = Xg + (size_t)bh * kCS * kDH;
  const float* Ab = Ag + (size_t)bh * kCS;
  const float* Bb = Bg + (size_t)bh * kCS * kDS;
  const float* Hb = Hg + (size_t)bh * kDS * kDH;

  if (role == 2) {
    // ======================= h_end path (8-wave MFMA GEMM) =======================
    float* ac   = (float*)(smem + OFF_AC);
    short* BThi = (short*)(smem + HOFF_BT);
    short* BTlo = (short*)(smem + HOFF_BTLO);
    short* XThi = (short*)(smem + HOFF_XT);
    short* XTlo = (short*)(smem + HOFF_XTLO);
    float* Ob = hend + (size_t)bh * kDS * kDH;

    float v = 0.f;
    if (tid < 256) {
      v = Ab[tid];
#pragma unroll
      for (int off = 1; off < 64; off <<= 1) {
        float t = __shfl_up(v, off);
        if (lane >= off) v += t;
      }
      float* wsum = (float*)(smem + HOFF_BT);
      if (lane == 63) wsum[w] = v;
    }
    __syncthreads();
    if (tid < 256) {
      const float* wsum = (const float*)(smem + HOFF_BT);
      float base = 0.f;
#pragma unroll
      for (int k = 0; k < 4; ++k)
        if (k < w) base += wsum[k];
      ac[tid] = v + base;
    }
    __syncthreads();
    const float alast = ac[kCS - 1];
    if (tid == 0) dtot[bh] = __expf(alast);

    f32x4 acc[4];
#pragma unroll
    for (int dg = 0; dg < 4; ++dg)
#pragma unroll
      for (int r = 0; r < 4; ++r) acc[dg][r] = 0.f;

    const int sblk = tid & 31;
    const int tq = (tid >> 5) & 7;
    const int st = w * 16 + fr;

    for (int t0 = 0; t0 < kCS; t0 += 32) {
      if (tid < 256) {
        // stage B^T [128s][32t] hi/lo via 4x4 micro-transpose
        F4 hr[4];
#pragma unroll
        for (int r = 0; r < 4; ++r)
          hr[r].v = *(const float4*)&Bb[(size_t)(t0 + tq * 4 + r) * kDS + sblk * 4];
#pragma unroll
        for (int c = 0; c < 4; ++c) {
          const int s2 = sblk * 4 + c;
          unsigned h0, h1, l0, l1;
          split2(hr[0].f[c], hr[1].f[c], h0, l0);
          split2(hr[2].f[c], hr[3].f[c], h1, l1);
          const int off = s2 * 32 + (((tq >> 1) ^ ((s2 >> 2) & 3)) << 3) + ((tq & 1) << 2);
          ((unsigned*)&BThi[off])[0] = h0;
          ((unsigned*)&BThi[off])[1] = h1;
          ((unsigned*)&BTlo[off])[0] = l0;
          ((unsigned*)&BTlo[off])[1] = l1;
        }
      } else {
        // stage weighted X^T [64d][32t] hi/lo
        const int t2 = tid - 256;
        const int d = t2 & 63;
        const int wx = t2 >> 6;
        const float* xp = &Xb[(size_t)(t0 + wx * 8) * kDH + d];
        const float* ap = &ac[t0 + wx * 8];
        float w0 = __expf(alast - ap[0]), w1 = __expf(alast - ap[1]);
        float w2 = __expf(alast - ap[2]), w3 = __expf(alast - ap[3]);
        float w4 = __expf(alast - ap[4]), w5 = __expf(alast - ap[5]);
        float w6 = __expf(alast - ap[6]), w7 = __expf(alast - ap[7]);
        s16x8 h8, l8;
        split8s(xp[0 * kDH] * w0, xp[1 * kDH] * w1, xp[2 * kDH] * w2, xp[3 * kDH] * w3,
                xp[4 * kDH] * w4, xp[5 * kDH] * w5, xp[6 * kDH] * w6, xp[7 * kDH] * w7,
                h8, l8);
        const int off = d * 32 + ((wx ^ ((d >> 2) & 3)) << 3);
        *(s16x8*)&XThi[off] = h8;
        *(s16x8*)&XTlo[off] = l8;
      }
      __syncthreads();
      const int aoff = st * 32 + ((fg ^ ((st >> 2) & 3)) << 3);
      s16x8 ah = *(const s16x8*)&BThi[aoff];
      s16x8 al = *(const s16x8*)&BTlo[aoff];
#pragma unroll
      for (int dg = 0; dg < 4; ++dg) {
        const int drow = dg * 16 + fr;
        const int xoff = drow * 32 + ((fg ^ ((drow >> 2) & 3)) << 3);
        s16x8 xh = *(const s16x8*)&XThi[xoff];
        s16x8 xl = *(const s16x8*)&XTlo[xoff];
        acc[dg] = __builtin_amdgcn_mfma_f32_16x16x32_bf16(ah, xh, acc[dg], 0, 0, 0);
        acc[dg] = __builtin_amdgcn_mfma_f32_16x16x32_bf16(ah, xl, acc[dg], 0, 0, 0);
        acc[dg] = __builtin_amdgcn_mfma_f32_16x16x32_bf16(al, xh, acc[dg], 0, 0, 0);
      }
      __syncthreads();
    }
    const float dscale = kAlpha * __expf(alast);
    const float sc = 1.f - kAlpha;
#pragma unroll
    for (int dg = 0; dg < 4; ++dg) {
#pragma unroll
      for (int r = 0; r < 4; ++r) {
        const int s = w * 16 + fg * 4 + r;
        const int d = dg * 16 + fr;
        Ob[(size_t)s * kDH + d] = dscale * Hb[(size_t)s * kDH + d] + sc * acc[dg][r];
      }
    }
    return;
  }

  // ======================= Y path (paired i-tiles) =======================
  const int itA = role;            // 0 or 1
  const int itB = 3 - role;        // 3 or 2
  const int i0A = itA * 64, i0B = itB * 64;
  const int jt_n = 2 * itB + 2;    // 8 or 6
  const int jtA_n = 2 * itA + 2;   // 2 or 4
  const bool gB = w >= 4;
  const int wl = w & 3;
  const int i0g = gB ? i0B : i0A;

  float* ac   = (float*)(smem + OFF_AC);
  float* eneg = (float*)(smem + OFF_ENEG);
  short* Bhi  = (short*)(smem + OFF_B);
  short* Blo  = (short*)(smem + OFF_BLO);
  short* XThi = (short*)(smem + OFF_XT);
  short* XTlo = (short*)(smem + OFF_XTLO);
  short* Sall = (short*)(smem + OFF_S);
  short* HThi = (short*)(smem + OFF_B);   // [64][128] h_prev^T hi (16KB)
  short* HTlo = (short*)(smem + OFF_XT);  // lo (16KB)

  const float* Cg_b = Cg + (size_t)bh * kCS * kDS;
  float* Yb = Yg + (size_t)bh * kCS * kDH;

  // ---- cumsum via wave shuffle scan (waves 0-3)
  {
    float v = 0.f;
    if (tid < 256) {
      v = Ab[tid];
#pragma unroll
      for (int off = 1; off < 64; off <<= 1) {
        float t = __shfl_up(v, off);
        if (lane >= off) v += t;
      }
      float* wsum = (float*)(smem + OFF_S);
      if (lane == 63) wsum[w] = v;
    }
    __syncthreads();
    if (tid < 256) {
      const float* wsum = (const float*)(smem + OFF_S);
      float base = 0.f;
#pragma unroll
      for (int k = 0; k < 4; ++k)
        if (k < w) base += wsum[k];
      const float a = v + base;
      ac[tid] = a;
      eneg[tid] = __expf(-a);
    }
    __syncthreads();
  }

  const int irow0 = i0g + wl * 16;   // this wave's 16 i-rows
  float eaci[4];
#pragma unroll
  for (int r = 0; r < 4; ++r) eaci[r] = __expf(ac[irow0 + fg * 4 + r]);

  // ---- jt=0 prefetch (uniform across 512 threads), issued first
  const int brow = tid >> 4;       // 0..31
  const int bg = tid & 15;
  const int xd = lane;             // d index
  const int xq = w;                // t-quad 0..7
  float4 pb0, pb1;
  float px0, px1, px2, px3;
  {
    pb0 = *(const float4*)&Bb[(size_t)brow * kDS + bg * 8];
    pb1 = *(const float4*)&Bb[(size_t)brow * kDS + bg * 8 + 4];
    const float* xp = &Xb[(size_t)(xq * 4) * kDH + xd];
    px0 = xp[0 * kDH]; px1 = xp[1 * kDH]; px2 = xp[2 * kDH]; px3 = xp[3 * kDH];
  }

  // ---- C fragments direct from global (read-once, per-wave 16 rows)
  s16x8 chi[4], clo[4];
  {
    const float* crow = &Cg_b[(size_t)(irow0 + fr) * kDS];
#pragma unroll
    for (int kc = 0; kc < 4; ++kc) {
      F4 u0, u1;
      u0.v = *(const float4*)&crow[kc * 32 + fg * 8];
      u1.v = *(const float4*)&crow[kc * 32 + fg * 8 + 4];
      split8v(u0.v, u1.v, chi[kc], clo[kc]);
    }
  }

  f32x4 yacc[4];
#pragma unroll
  for (int n = 0; n < 4; ++n)
#pragma unroll
    for (int r = 0; r < 4; ++r) yacc[n][r] = 0.f;

  short* Sp = Sall + w * 512;  // per-wave S~ plane [16][32]

  for (int jt = 0; jt < jt_n; ++jt) {
    // ---- split+write current tile from named prefetch regs (all threads)
    {
      s16x8 h8, l8;
      split8v(pb0, pb1, h8, l8);
      const int col = (bg ^ (brow & 7)) * 8;
      *(s16x8*)&Bhi[brow * 128 + col] = h8;
      *(s16x8*)&Blo[brow * 128 + col] = l8;
    }
    {
      unsigned h0, h1, l0, l1;
      split2(px0, px1, h0, l0);
      split2(px2, px3, h1, l1);
      const int off = xd * 32 + (((xq >> 1) ^ ((xd >> 2) & 3)) << 3) + ((xq & 1) << 2);
      ((unsigned*)&XThi[off])[0] = h0;
      ((unsigned*)&XThi[off])[1] = h1;
      ((unsigned*)&XTlo[off])[0] = l0;
      ((unsigned*)&XTlo[off])[1] = l1;
    }
    // ---- issue next tile's loads; stay in flight across both lds_barriers
    if (jt + 1 < jt_n) {
      const int j0n = (jt + 1) * 32;
      pb0 = *(const float4*)&Bb[(size_t)(j0n + brow) * kDS + bg * 8];
      pb1 = *(const float4*)&Bb[(size_t)(j0n + brow) * kDS + bg * 8 + 4];
      const float* xp = &Xb[(size_t)(j0n + xq * 4) * kDH + xd];
      px0 = xp[0 * kDH]; px1 = xp[1 * kDH]; px2 = xp[2 * kDH]; px3 = xp[3 * kDH];
    }
    lds_barrier();

    // group A computes only within its causal span; group B always
    if (gB || jt < jtA_n) {
      const int j0 = jt * 32;
      // ---- S = C·B^T (split: Chi·Bhi + Chi·Blo + Clo·Bhi)
      f32x4 s[2];
#pragma unroll
      for (int n = 0; n < 2; ++n) {
#pragma unroll
        for (int r = 0; r < 4; ++r) s[n][r] = 0.f;
        const int jrow = n * 16 + fr;
        const short* bph = &Bhi[jrow * 128];
        const short* bpl = &Blo[jrow * 128];
#pragma unroll
        for (int kc = 0; kc < 4; ++kc) {
          const int phys = ((4 * kc + fg) ^ (jrow & 7)) * 8;
          s16x8 b8 = *(const s16x8*)&bph[phys];
          s16x8 l8 = *(const s16x8*)&bpl[phys];
          s[n] = __builtin_amdgcn_mfma_f32_16x16x32_bf16(chi[kc], b8, s[n], 0, 0, 0);
          s[n] = __builtin_amdgcn_mfma_f32_16x16x32_bf16(chi[kc], l8, s[n], 0, 0, 0);
          s[n] = __builtin_amdgcn_mfma_f32_16x16x32_bf16(clo[kc], b8, s[n], 0, 0, 0);
        }
      }
      // ---- mask + decay, write S~ to per-wave plane
#pragma unroll
      for (int n = 0; n < 2; ++n) {
        const int jg = j0 + n * 16 + fr;
        const float enj = eneg[jg];
#pragma unroll
        for (int r = 0; r < 4; ++r) {
          const int iwl = fg * 4 + r;
          const int ig = irow0 + iwl;
          float sv = s[n][r] * eaci[r] * enj;
          sv = (jg <= ig) ? sv : 0.f;
          Sp[iwl * 32 + (((n * 2 + (fr >> 3)) ^ fg) << 3) + (fr & 7)] = (short)bf16_1(sv);
        }
      }
      // ---- PV: Y += S~ · X
      {
        s16x8 sa = *(const s16x8*)&Sp[fr * 32 + ((fg ^ (fr >> 2)) << 3)];
#pragma unroll
        for (int n = 0; n < 4; ++n) {
          const int drow = n * 16 + fr;
          const int pxo = (fg ^ ((drow >> 2) & 3)) << 3;
          s16x8 xh = *(const s16x8*)&XThi[drow * 32 + pxo];
          s16x8 xl = *(const s16x8*)&XTlo[drow * 32 + pxo];
          yacc[n] = __builtin_amdgcn_mfma_f32_16x16x32_bf16(sa, xh, yacc[n], 0, 0, 0);
          yacc[n] = __builtin_amdgcn_mfma_f32_16x16x32_bf16(sa, xl, yacc[n], 0, 0, 0);
        }
      }
    }
    lds_barrier();
  }

  // ---- Yh = C · h_prev: full h_prev^T staged once (512 thr), all waves MFMA
  {
    const int dd = tid & 15, tt = tid >> 4;  // tt 0..31 -> full 128 s
    F4 hr[4];
#pragma unroll
    for (int r = 0; r < 4; ++r)
      hr[r].v = *(const float4*)&Hb[(size_t)(tt * 4 + r) * kDH + dd * 4];
#pragma unroll
    for (int c = 0; c < 4; ++c) {
      const int d = dd * 4 + c;
      unsigned h0, h1, l0, l1;
      split2(hr[0].f[c], hr[1].f[c], h0, l0);
      split2(hr[2].f[c], hr[3].f[c], h1, l1);
      const int off = d * 128 + (((tt >> 1) ^ (d & 7)) << 3) + ((tt & 1) << 2);
      ((unsigned*)&HThi[off])[0] = h0;
      ((unsigned*)&HThi[off])[1] = h1;
      ((unsigned*)&HTlo[off])[0] = l0;
      ((unsigned*)&HTlo[off])[1] = l1;
    }
  }
  __syncthreads();

  f32x4 yh[4];
#pragma unroll
  for (int n = 0; n < 4; ++n)
#pragma unroll
    for (int r = 0; r < 4; ++r) yh[n][r] = 0.f;

#pragma unroll
  for (int kc = 0; kc < 4; ++kc) {
#pragma unroll
    for (int n = 0; n < 4; ++n) {
      const int drow = n * 16 + fr;
      const int phys = ((4 * kc + fg) ^ (drow & 7)) * 8;
      s16x8 hh = *(const s16x8*)&HThi[drow * 128 + phys];
      s16x8 hl = *(const s16x8*)&HTlo[drow * 128 + phys];
      yh[n] = __builtin_amdgcn_mfma_f32_16x16x32_bf16(chi[kc], hh, yh[n], 0, 0, 0);
      yh[n] = __builtin_amdgcn_mfma_f32_16x16x32_bf16(chi[kc], hl, yh[n], 0, 0, 0);
      yh[n] = __builtin_amdgcn_mfma_f32_16x16x32_bf16(clo[kc], hh, yh[n], 0, 0, 0);
    }
  }

  // ---- epilogue: Y = (1-a)*Y_intra + a*exp(ac_i)*Yh
#pragma unroll
  for (int n = 0; n < 4; ++n) {
#pragma unroll
    for (int r = 0; r < 4; ++r) {
      const int ig = irow0 + fg * 4 + r;
      const int d = n * 16 + fr;
      Yb[(size_t)ig * kDH + d] = (1.f - kAlpha) * yacc[n][r] + (kAlpha * eaci[r]) * yh[n][r];
    }
  }
}

extern "C" void kernel_launch(void* const* d_in, const int* in_sizes, int n_in,
                              void* d_out, int out_size, void* d_ws, size_t ws_size,
                              hipStream_t stream) {
  const float* X = (const float*)d_in[0];
  const float* A = (const float*)d_in[1];
  const float* B = (const float*)d_in[2];
  const float* C = (const float*)d_in[3];
  const float* H = (const float*)d_in[4];
  float* out = (float*)d_out;
  float* Y = out;
  float* hend = Y + (size_t)kBH * kCS * kDH;
  float* dt = hend + (size_t)kBH * kDS * kDH;

  fused_kernel<<<1536, 512, 0, stream>>>(X, A, B, C, H, Y, hend, dt);
}